// Round 10
// baseline (322.200 us; speedup 1.0000x reference)
//
#include <hip/hip_runtime.h>
#include <hip/hip_bf16.h>

#define HIDC 768
#define Hh   6
#define Dd   64
#define AHc  384
#define KSc  9
#define PADc 4
#define Bb   4
#define Ss   1024
#define MRr  (Bb * Ss)          // 4096

typedef __attribute__((ext_vector_type(8))) __bf16 bf16x8;
typedef __attribute__((ext_vector_type(4))) float  f32x4;

// split 8 consecutive f32 into hi/lo bf16 fragments
__device__ __forceinline__ void split8(const float* p, bf16x8& hi, bf16x8& lo) {
    float4 x0 = *(const float4*)p;
    float4 x1 = *(const float4*)(p + 4);
    float xs[8] = {x0.x, x0.y, x0.z, x0.w, x1.x, x1.y, x1.z, x1.w};
#pragma unroll
    for (int e = 0; e < 8; ++e) {
        __bf16 hv = (__bf16)xs[e];
        hi[e] = hv;
        lo[e] = (__bf16)(xs[e] - (float)hv);
    }
}

__device__ __forceinline__ void split8r(const float* xs, bf16x8& hi, bf16x8& lo) {
#pragma unroll
    for (int e = 0; e < 8; ++e) {
        __bf16 hv = (__bf16)xs[e];
        hi[e] = hv;
        lo[e] = (__bf16)(xs[e] - (float)hv);
    }
}

// convert 8 consecutive f32 to bf16 (hi only)
__device__ __forceinline__ bf16x8 cvt8(const float* p) {
    float4 x0 = *(const float4*)p;
    float4 x1 = *(const float4*)(p + 4);
    float xs[8] = {x0.x, x0.y, x0.z, x0.w, x1.x, x1.y, x1.z, x1.w};
    bf16x8 h;
#pragma unroll
    for (int e = 0; e < 8; ++e) h[e] = (__bf16)xs[e];
    return h;
}

// ---------------- depthwise conv over sequence (float4 over channels) ----------------
__global__ void k_depthwise(const float* __restrict__ Kin, const float* __restrict__ dww,
                            float* __restrict__ dwseq) {
    int idx = blockIdx.x * 256 + threadIdx.x;      // over B*S*HID/4
    if (idx >= Bb * Ss * HIDC / 4) return;
    int c4 = idx % (HIDC / 4);
    int s  = (idx / (HIDC / 4)) % Ss;
    int b  = idx / ((HIDC / 4) * Ss);
    int c  = c4 * 4;
    float wv[4][KSc];
#pragma unroll
    for (int j = 0; j < 4; ++j)
#pragma unroll
        for (int k = 0; k < KSc; ++k) wv[j][k] = dww[(c + j) * KSc + k];
    float4 acc = {0.f, 0.f, 0.f, 0.f};
#pragma unroll
    for (int k = 0; k < KSc; ++k) {
        int sp = s + k - PADc;
        if (sp >= 0 && sp < Ss) {
            float4 v = *(const float4*)&Kin[(size_t)(b * Ss + sp) * HIDC + c];
            acc.x += v.x * wv[0][k]; acc.y += v.y * wv[1][k];
            acc.z += v.z * wv[2][k]; acc.w += v.w * wv[3][k];
        }
    }
    *(float4*)&dwseq[(size_t)idx * 4] = acc;
}

// ---------------- transposed weight split (z=0..3): LDS-tiled ----------------
__global__ __launch_bounds__(256) void k_wsplit_t(const float* __restrict__ Wq, const float* __restrict__ Wk,
                                                  const float* __restrict__ Wv, const float* __restrict__ coW,
                                                  __bf16* __restrict__ Whi, __bf16* __restrict__ Wlo) {
    int z = blockIdx.z;
    const float* src = (z == 0) ? Wq : (z == 1) ? Wk : (z == 2) ? Wv : coW;
    int n0 = blockIdx.x * 64, k0 = blockIdx.y * 64;
    int tid = threadIdx.x;
    int r = tid >> 2, cq = tid & 3;
    __shared__ float tile[64][65];      // tile[k_local][n_local]
#pragma unroll
    for (int e = 0; e < 4; ++e) {
        float4 v = *(const float4*)&src[(size_t)(k0 + r) * AHc + n0 + cq * 16 + e * 4];
        tile[r][cq * 16 + e * 4 + 0] = v.x;
        tile[r][cq * 16 + e * 4 + 1] = v.y;
        tile[r][cq * 16 + e * 4 + 2] = v.z;
        tile[r][cq * 16 + e * 4 + 3] = v.w;
    }
    __syncthreads();
    float x[16];
#pragma unroll
    for (int e = 0; e < 16; ++e) x[e] = tile[cq * 16 + e][r];
    bf16x8 h0, l0, h1, l1;
    split8r(x, h0, l0);
    split8r(x + 8, h1, l1);
    size_t dst = ((size_t)(z * AHc + n0 + r)) * HIDC + k0 + cq * 16;
    *(bf16x8*)(Whi + dst)     = h0;
    *(bf16x8*)(Whi + dst + 8) = h1;
    *(bf16x8*)(Wlo + dst)     = l0;
    *(bf16x8*)(Wlo + dst + 8) = l1;
}

// ---------------- pw_w split (z=4, already [n][k]) ----------------
__global__ void k_wsplit_c(const float* __restrict__ pww,
                           __bf16* __restrict__ Whi, __bf16* __restrict__ Wlo) {
    int idx = blockIdx.x * 256 + threadIdx.x;      // over AHc*HIDC/8
    if (idx >= AHc * HIDC / 8) return;
    bf16x8 hi, lo;
    split8(pww + (size_t)idx * 8, hi, lo);
    size_t dst = (size_t)4 * AHc * HIDC + (size_t)idx * 8;
    *(bf16x8*)(Whi + dst) = hi;
    *(bf16x8*)(Wlo + dst) = lo;
}

// ---------------- Q/K split for k_attn: qh (hi only), kh+kl ----------------
__global__ void k_qksplit(const float* __restrict__ mq, const float* __restrict__ mk,
                          __bf16* __restrict__ qh, __bf16* __restrict__ kh,
                          __bf16* __restrict__ kl) {
    const int n8 = MRr * AHc / 8;
    int idx = blockIdx.x * 256 + threadIdx.x;
    if (idx >= 2 * n8) return;
    int which = idx / n8, i8 = idx % n8;
    if (which == 0) {
        *(bf16x8*)(qh + (size_t)i8 * 8) = cvt8(mq + (size_t)i8 * 8);
    } else {
        bf16x8 hi, lo;
        split8(mk + (size_t)i8 * 8, hi, lo);
        *(bf16x8*)(kh + (size_t)i8 * 8) = hi;
        *(bf16x8*)(kl + (size_t)i8 * 8) = lo;
    }
}

// ---------------- V transpose (hi bf16 only): vt[(b*H+h)*D + d][s] = mv[b*S+s][h*D+d] ----
// Deliberately formula-direct (no LDS tiling): one thread per output bf16x8 (8 s's,
// fixed d). Reads are strided f32 (L2-bound); writes are contiguous 16 B.
__global__ void k_vtr(const float* __restrict__ mv, __bf16* __restrict__ vt) {
    int idx = blockIdx.x * 256 + threadIdx.x;      // over MRr*AHc/8
    if (idx >= MRr * AHc / 8) return;
    int s8 = idx & 127;              // Ss/8 = 128
    int rest = idx >> 7;
    int d = rest & 63;
    int bh = rest >> 6;              // b*Hh + h, in [0, 24)
    int b = bh / Hh, h = bh % Hh;
    const float* src = mv + (size_t)(b * Ss + s8 * 8) * AHc + h * Dd + d;
    bf16x8 v;
#pragma unroll
    for (int e = 0; e < 8; ++e) v[e] = (__bf16)src[(size_t)e * AHc];
    *(bf16x8*)(vt + ((size_t)bh * Dd + d) * Ss + s8 * 8) = v;
}

// ---------------- bias buffer: [5][384] ----------------
__global__ void k_bias(const float* __restrict__ cob, const float* __restrict__ sepb,
                       float* __restrict__ biasb) {
    int idx = blockIdx.x * 256 + threadIdx.x;
    if (idx >= 5 * AHc) return;
    int z = idx / AHc, n = idx % AHc;
    biasb[idx] = (z == 3) ? cob[n] : (z == 4) ? sepb[n] : 0.f;
}

// ---------------- batched MFMA GEMM (2-term: ah*bh + ah*bl) ----------------
__global__ __launch_bounds__(256) void k_gemm5(
        const float* __restrict__ Q, const float* __restrict__ Kin,
        const float* __restrict__ V, const float* __restrict__ dwseq,
        const __bf16* __restrict__ Whi, const __bf16* __restrict__ Wlo,
        const float* __restrict__ biasb, float* __restrict__ Call) {
    __shared__ __attribute__((aligned(16))) __bf16 As_hi[128 * 40];
    __shared__ __attribute__((aligned(16))) __bf16 Bs_hi[128 * 40];
    __shared__ __attribute__((aligned(16))) __bf16 Bs_lo[128 * 40];

    int z = blockIdx.z;
    const float* Asrc = (z == 0) ? Q : (z == 1) ? Kin : (z <= 3) ? V : dwseq;
    int m0 = blockIdx.y * 128, n0 = blockIdx.x * 128;
    int tid = threadIdx.x;
    int wave = tid >> 6, lane = tid & 63, quad = lane >> 4, l15 = lane & 15;

    int sr = tid >> 1;
    int sk = (tid & 1) * 16;
    const float* Arow = Asrc + (size_t)(m0 + sr) * HIDC + sk;
    const __bf16* BhiRow = Whi + ((size_t)(z * AHc + n0 + sr)) * HIDC + sk;
    const __bf16* BloRow = Wlo + ((size_t)(z * AHc + n0 + sr)) * HIDC + sk;

    f32x4 acc[4][4] = {};

    for (int k0 = 0; k0 < HIDC; k0 += 32) {
        const float* ap = Arow + k0;
        *(bf16x8*)&As_hi[sr * 40 + sk]     = cvt8(ap);
        *(bf16x8*)&As_hi[sr * 40 + sk + 8] = cvt8(ap + 8);
        {
            const __bf16* bh = BhiRow + k0;
            const __bf16* bl = BloRow + k0;
            *(bf16x8*)&Bs_hi[sr * 40 + sk]     = *(const bf16x8*)bh;
            *(bf16x8*)&Bs_hi[sr * 40 + sk + 8] = *(const bf16x8*)(bh + 8);
            *(bf16x8*)&Bs_lo[sr * 40 + sk]     = *(const bf16x8*)bl;
            *(bf16x8*)&Bs_lo[sr * 40 + sk + 8] = *(const bf16x8*)(bl + 8);
        }
        __syncthreads();

        int mrow = (wave >> 1) * 64 + l15;
        int nrow = (wave & 1) * 64 + l15;
        bf16x8 ah[4], bh[4], bl[4];
#pragma unroll
        for (int mt = 0; mt < 4; ++mt)
            ah[mt] = *(bf16x8*)&As_hi[(mrow + mt * 16) * 40 + quad * 8];
#pragma unroll
        for (int nt = 0; nt < 4; ++nt) {
            bh[nt] = *(bf16x8*)&Bs_hi[(nrow + nt * 16) * 40 + quad * 8];
            bl[nt] = *(bf16x8*)&Bs_lo[(nrow + nt * 16) * 40 + quad * 8];
        }
#pragma unroll
        for (int mt = 0; mt < 4; ++mt)
#pragma unroll
            for (int nt = 0; nt < 4; ++nt) {
                acc[mt][nt] = __builtin_amdgcn_mfma_f32_16x16x32_bf16(ah[mt], bh[nt], acc[mt][nt], 0, 0, 0);
                acc[mt][nt] = __builtin_amdgcn_mfma_f32_16x16x32_bf16(ah[mt], bl[nt], acc[mt][nt], 0, 0, 0);
            }
        __syncthreads();
    }

    float* Cz = Call + (size_t)z * MRr * AHc;
    const float* bz = biasb + z * AHc;
#pragma unroll
    for (int nt = 0; nt < 4; ++nt) {
        int n = n0 + (wave & 1) * 64 + nt * 16 + l15;
        float bias = bz[n];
#pragma unroll
        for (int mt = 0; mt < 4; ++mt) {
#pragma unroll
            for (int r = 0; r < 4; ++r) {
                int m = m0 + (wave >> 1) * 64 + mt * 16 + quad * 4 + r;
                Cz[(size_t)m * AHc + n] = acc[mt][nt][r] + bias;
            }
        }
    }
}

// ---------------- conv_attn -> ck linear -> per-head softmax over KS ----------------
__global__ __launch_bounds__(64) void k_ck(const float* __restrict__ mkc, const float* __restrict__ mq,
                                           const float* __restrict__ ckW, const float* __restrict__ ckb,
                                           float* __restrict__ ck_sm) {
    int row = blockIdx.x;            // b*S + s
    int tid = threadIdx.x;
    __shared__ float ca[AHc];
    __shared__ float ckv[Hh * KSc];
    for (int o = tid; o < AHc; o += 64)
        ca[o] = mkc[row * AHc + o] * mq[row * AHc + o];
    __syncthreads();
    if (tid < Hh * KSc) {
        float acc = ckb[tid];
        for (int o = 0; o < AHc; ++o)
            acc += ca[o] * ckW[o * (Hh * KSc) + tid];
        ckv[tid] = acc;
    }
    __syncthreads();
    if (tid < Hh) {
        float m = -3e38f;
#pragma unroll
        for (int k = 0; k < KSc; ++k) m = fmaxf(m, ckv[tid * KSc + k]);
        float e[KSc];
        float s = 0.f;
#pragma unroll
        for (int k = 0; k < KSc; ++k) { e[k] = expf(ckv[tid * KSc + k] - m); s += e[k]; }
        float inv = 1.f / s;
#pragma unroll
        for (int k = 0; k < KSc; ++k) ck_sm[(row * Hh + tid) * KSc + k] = e[k] * inv;
    }
}

// ---------------- dynamic conv output (float4) -> out[.., AH + h*D + d] ----------------
__global__ void k_convout(const float* __restrict__ co, const float* __restrict__ ck_sm,
                          float* __restrict__ out) {
    int idx = blockIdx.x * 256 + threadIdx.x;       // over B*S*AH/4
    if (idx >= Bb * Ss * AHc / 4) return;
    int d4 = idx & 15;
    int h  = (idx >> 4) % Hh;
    int s  = (idx / (AHc / 4)) % Ss;
    int b  = idx / ((AHc / 4) * Ss);
    int row = b * Ss + s;
    const float* ck = ck_sm + (size_t)(row * Hh + h) * KSc;
    float4 acc = {0.f, 0.f, 0.f, 0.f};
#pragma unroll
    for (int k = 0; k < KSc; ++k) {
        int sp = s + k - PADc;
        if (sp >= 0 && sp < Ss) {
            float4 v = *(const float4*)&co[(size_t)(b * Ss + sp) * AHc + h * Dd + d4 * 4];
            float wv = ck[k];
            acc.x += wv * v.x; acc.y += wv * v.y; acc.z += wv * v.z; acc.w += wv * v.w;
        }
    }
    *(float4*)&out[(size_t)row * (2 * AHc) + AHc + h * Dd + d4 * 4] = acc;
}

// ---------------- per-batch td softmax row ----------------
__global__ __launch_bounds__(256) void k_td(const float* __restrict__ td, const int* __restrict__ mask,
                                            float* __restrict__ td_sm) {
    int b = blockIdx.x;
    int tid = threadIdx.x;
    __shared__ float red[256];
    __shared__ float tv[Ss];
    float ls = 0.f;
    for (int j = tid; j < Ss; j += 256) {
        float v = td[b * Ss + j];
        tv[j] = v;
        ls += v * v;
    }
    red[tid] = ls; __syncthreads();
    for (int s = 128; s > 0; s >>= 1) { if (tid < s) red[tid] += red[tid + s]; __syncthreads(); }
    float norm = fmaxf(sqrtf(red[0]), 1e-12f);
    __syncthreads();
    float lm = -3e38f;
    for (int j = tid; j < Ss; j += 256) {
        float v = mask[b * Ss + j] ? tv[j] / norm : -1e4f;
        tv[j] = v;
        lm = fmaxf(lm, v);
    }
    red[tid] = lm; __syncthreads();
    for (int s = 128; s > 0; s >>= 1) { if (tid < s) red[tid] = fmaxf(red[tid], red[tid + s]); __syncthreads(); }
    float m = red[0]; __syncthreads();
    float lsum = 0.f;
    for (int j = tid; j < Ss; j += 256) {
        float e = expf(tv[j] - m);
        tv[j] = e;
        lsum += e;
    }
    red[tid] = lsum; __syncthreads();
    for (int s = 128; s > 0; s >>= 1) { if (tid < s) red[tid] += red[tid + s]; __syncthreads(); }
    float inv = 1.f / red[0];
    __syncthreads();
    for (int j = tid; j < Ss; j += 256)
        td_sm[b * Ss + j] = tv[j] * inv;
}

// ---------------- attention: 2-term MFMA QK^T + wave softmax + 2-term MFMA PV (vT) ------
__device__ __forceinline__ int sidx(int m, int j) {
    return m * 1024 + (j & ~15) + ((j ^ (j >> 6) ^ m) & 15);
}

__global__ __launch_bounds__(256) void k_attn(const __bf16* __restrict__ qh,
                                              const __bf16* __restrict__ kh, const __bf16* __restrict__ kl,
                                              const __bf16* __restrict__ vt,
                                              const int* __restrict__ mask,
                                              const float* __restrict__ td_sm, const float* __restrict__ gammas,
                                              float* __restrict__ out) {
    __shared__ float sc[16 * 1024];      // 64 KB exactly
    int i0 = blockIdx.x * 16;
    int h = blockIdx.y % Hh, b = blockIdx.y / Hh;
    int tid = threadIdx.x;
    int w = tid >> 6, lane = tid & 63, quad = lane >> 4, l15 = lane & 15;
    int jw = w * 256;                     // this wave's j-range [jw, jw+256)

    // ---- phase 1: QK^T via MFMA: q_hi*(k_hi + k_lo) ----
    bf16x8 a_hi[2];
    {
        size_t qoff = (size_t)(b * Ss + i0 + l15) * AHc + h * Dd + quad * 8;
        a_hi[0] = *(const bf16x8*)(qh + qoff);
        a_hi[1] = *(const bf16x8*)(qh + qoff + 32);
    }
#pragma unroll 2
    for (int t = 0; t < 16; ++t) {
        int jt = jw + t * 16;
        size_t koff = (size_t)(b * Ss + jt + l15) * AHc + h * Dd + quad * 8;
        f32x4 acc = {0.f, 0.f, 0.f, 0.f};
#pragma unroll
        for (int kc = 0; kc < 2; ++kc) {
            bf16x8 khv = *(const bf16x8*)(kh + koff + kc * 32);
            bf16x8 klv = *(const bf16x8*)(kl + koff + kc * 32);
            acc = __builtin_amdgcn_mfma_f32_16x16x32_bf16(a_hi[kc], khv, acc, 0, 0, 0);
            acc = __builtin_amdgcn_mfma_f32_16x16x32_bf16(a_hi[kc], klv, acc, 0, 0, 0);
        }
#pragma unroll
        for (int r = 0; r < 4; ++r)
            sc[sidx(quad * 4 + r, jt + l15)] = acc[r] * 0.125f;   // C: col=l15, row=quad*4+r
    }
    __syncthreads();

    // ---- phase 2: softmax -> cumsum -> decay -> softmax2, wave owns rows w*4..w*4+3 ----
    const int* mrow = mask + b * Ss;
    const float* tdrow = td_sm + b * Ss;
    float gamma = -log1pf(expf(gammas[h]));   // -softplus
    int jb = lane << 4;
    int marr[16];
    {
        const int4* mp = (const int4*)(mrow + jb);
#pragma unroll
        for (int k = 0; k < 4; ++k) ((int4*)marr)[k] = mp[k];
    }
    float tdv[16];
    {
        const float4* tp = (const float4*)(tdrow + jb);
#pragma unroll
        for (int k = 0; k < 4; ++k) ((float4*)tdv)[k] = tp[k];
    }

#pragma unroll
    for (int r4 = 0; r4 < 4; ++r4) {
        int m = w * 4 + r4;
        int i = i0 + m;
        float s[16], p[16];
#pragma unroll
        for (int jj = 0; jj < 16; ++jj) s[jj] = sc[sidx(m, jb + jj)];
        float mx = -1e30f;
#pragma unroll
        for (int jj = 0; jj < 16; ++jj) mx = fmaxf(mx, marr[jj] ? s[jj] : -1e30f);
        mx = fmaxf(mx, __shfl_xor(mx, 1));  mx = fmaxf(mx, __shfl_xor(mx, 2));
        mx = fmaxf(mx, __shfl_xor(mx, 4));  mx = fmaxf(mx, __shfl_xor(mx, 8));
        mx = fmaxf(mx, __shfl_xor(mx, 16)); mx = fmaxf(mx, __shfl_xor(mx, 32));
#pragma unroll
        for (int jj = 0; jj < 16; ++jj) p[jj] = marr[jj] ? __expf(s[jj] - mx) : 0.f;
#pragma unroll
        for (int jj = 1; jj < 16; ++jj) p[jj] += p[jj - 1];
        float t = p[15];
        float incl = t;
#pragma unroll
        for (int dlt = 1; dlt < 64; dlt <<= 1) {
            float v = __shfl_up(incl, dlt);
            if (lane >= dlt) incl += v;
        }
        float off = incl - t;
        float tot = __shfl(incl, 63);
        float inv = 1.f / fmaxf(tot, 1e-30f);
        float mx2 = -1e30f;
#pragma unroll
        for (int jj = 0; jj < 16; ++jj) {
            int j = jb + jj;
            float cum = p[jj] + off;
            float pos = fabsf((float)(j - i));
            float ds = sqrtf(fmaxf((tot - cum) * inv * pos, 0.f));
            float te = fminf(fmaxf(__expf(ds * gamma), 1e-5f), 1e5f);
            float mult = te - ((j < i) ? tdv[jj] : 0.f);
            float s2 = marr[jj] ? s[jj] * mult : -1e8f;
            s[jj] = s2;
            mx2 = fmaxf(mx2, s2);
        }
        mx2 = fmaxf(mx2, __shfl_xor(mx2, 1));  mx2 = fmaxf(mx2, __shfl_xor(mx2, 2));
        mx2 = fmaxf(mx2, __shfl_xor(mx2, 4));  mx2 = fmaxf(mx2, __shfl_xor(mx2, 8));
        mx2 = fmaxf(mx2, __shfl_xor(mx2, 16)); mx2 = fmaxf(mx2, __shfl_xor(mx2, 32));
        float sm = 0.f;
#pragma unroll
        for (int jj = 0; jj < 16; ++jj) { s[jj] = __expf(s[jj] - mx2); sm += s[jj]; }
        sm += __shfl_xor(sm, 1);  sm += __shfl_xor(sm, 2);
        sm += __shfl_xor(sm, 4);  sm += __shfl_xor(sm, 8);
        sm += __shfl_xor(sm, 16); sm += __shfl_xor(sm, 32);
        float inv2 = 1.f / sm;
#pragma unroll
        for (int jj = 0; jj < 16; ++jj) sc[sidx(m, jb + jj)] = s[jj] * inv2;
    }
    __syncthreads();

    // ---- phase 3: PV via MFMA: (p_hi + p_lo) * v_hi; V^T bf16 [d][s] vector loads ----
    f32x4 oacc[4] = {};
    const __bf16* vtb = vt + (size_t)(b * Hh + h) * Dd * Ss;
#pragma unroll 2
    for (int kc = 0; kc < 8; ++kc) {
        int j0 = jw + kc * 32 + quad * 8;        // this lane's 8 j indices (k = quad*8+e)
        float x[8];
#pragma unroll
        for (int jj = 0; jj < 8; ++jj) x[jj] = sc[sidx(l15, j0 + jj)];
        bf16x8 p_hi, p_lo;
        split8r(x, p_hi, p_lo);
#pragma unroll
        for (int nt = 0; nt < 4; ++nt) {
            int d = nt * 16 + l15;
            bf16x8 vv = *(const bf16x8*)(vtb + (size_t)d * Ss + j0);
            oacc[nt] = __builtin_amdgcn_mfma_f32_16x16x32_bf16(p_hi, vv, oacc[nt], 0, 0, 0);
            oacc[nt] = __builtin_amdgcn_mfma_f32_16x16x32_bf16(p_lo, vv, oacc[nt], 0, 0, 0);
        }
    }
    __syncthreads();                      // all waves done reading sc before reuse
#pragma unroll
    for (int nt = 0; nt < 4; ++nt)
#pragma unroll
        for (int r = 0; r < 4; ++r)
            sc[w * 1024 + (quad * 4 + r) * 64 + nt * 16 + l15] = oacc[nt][r];
    __syncthreads();
#pragma unroll
    for (int e = 0; e < 4; ++e) {
        int idx = e * 256 + tid;
        int m = idx >> 6, dd = idx & 63;
        float v = sc[idx] + sc[1024 + idx] + sc[2048 + idx] + sc[3072 + idx];
        out[(size_t)(b * Ss + i0 + m) * (2 * AHc) + h * Dd + dd] = v;
    }
}

extern "C" void kernel_launch(void* const* d_in, const int* in_sizes, int n_in,
                              void* d_out, int out_size, void* d_ws, size_t ws_size,
                              hipStream_t stream) {
    const float* Q    = (const float*)d_in[0];
    const float* Kin  = (const float*)d_in[1];
    const float* V    = (const float*)d_in[2];
    const float* td   = (const float*)d_in[3];
    const int*   mask = (const int*)d_in[4];
    const float* Wq   = (const float*)d_in[5];
    const float* Wk   = (const float*)d_in[6];
    const float* Wv   = (const float*)d_in[7];
    const float* dww  = (const float*)d_in[8];
    const float* pww  = (const float*)d_in[9];
    const float* sepb = (const float*)d_in[10];
    const float* ckW  = (const float*)d_in[11];
    const float* ckb  = (const float*)d_in[12];
    const float* coW  = (const float*)d_in[13];
    const float* cob  = (const float*)d_in[14];
    const float* gam  = (const float*)d_in[15];
    float* out = (float*)d_out;
    float* ws = (float*)d_ws;

    float* mq    = ws;                              // z=0 C
    float* mk    = mq    + (size_t)MRr * AHc;       // z=1
    float* mv    = mk    + (size_t)MRr * AHc;       // z=2
    float* co    = mv    + (size_t)MRr * AHc;       // z=3
    float* mkc   = co    + (size_t)MRr * AHc;       // z=4
    float* dwseq = mkc   + (size_t)MRr * AHc;       // MR*HID f32 (dead after k_gemm5)
    float* cksm  = dwseq + (size_t)MRr * HIDC;      // MR*H*KS
    float* tdsm  = cksm  + (size_t)MRr * Hh * KSc;  // B*S
    float* biasb = tdsm  + (size_t)Bb * Ss;         // 5*384

    // d_out doubles as scratch for split weights (consumed by k_gemm5, then overwritten)
    __bf16* Whi = (__bf16*)d_out;
    __bf16* Wlo = Whi + (size_t)5 * AHc * HIDC;
    // qh/kh/kl/vt overlay the dead dwseq region: 4 * MR*AH bf16 == MR*HID f32 exactly
    __bf16* qh = (__bf16*)dwseq;
    __bf16* kh = qh + (size_t)MRr * AHc;
    __bf16* kl = kh + (size_t)MRr * AHc;
    __bf16* vt = kl + (size_t)MRr * AHc;

    dim3 gt(AHc / 64, HIDC / 64, 4);    // 6 x 12 x 4
    k_wsplit_t<<<gt, 256, 0, stream>>>(Wq, Wk, Wv, coW, Whi, Wlo);
    k_wsplit_c<<<(AHc * HIDC / 8 + 255) / 256, 256, 0, stream>>>(pww, Whi, Wlo);
    k_depthwise<<<(MRr * HIDC / 4 + 255) / 256, 256, 0, stream>>>(Kin, dww, dwseq);
    k_bias<<<(5 * AHc + 255) / 256, 256, 0, stream>>>(cob, sepb, biasb);

    dim3 gg(AHc / 128, MRr / 128, 5);   // 3 x 32 x 5
    k_gemm5<<<gg, 256, 0, stream>>>(Q, Kin, V, dwseq, Whi, Wlo, biasb, mq);

    k_qksplit<<<(2 * MRr * AHc / 8 + 255) / 256, 256, 0, stream>>>(mq, mk, qh, kh, kl);
    k_vtr<<<(MRr * AHc / 8 + 255) / 256, 256, 0, stream>>>(mv, vt);
    k_ck<<<MRr, 64, 0, stream>>>(mkc, mq, ckW, ckb, cksm);
    k_convout<<<(MRr * AHc / 4 + 255) / 256, 256, 0, stream>>>(co, cksm, out);
    k_td<<<Bb, 256, 0, stream>>>(td, mask, tdsm);

    dim3 ga(Ss / 16, Bb * Hh);          // 64 x 24
    k_attn<<<ga, 256, 0, stream>>>(qh, kh, kl, vt, mask, tdsm, gam, out);
}

// Round 11
// 308.779 us; speedup vs baseline: 1.0435x; 1.0435x over previous
//
#include <hip/hip_runtime.h>
#include <hip/hip_bf16.h>

#define HIDC 768
#define Hh   6
#define Dd   64
#define AHc  384
#define KSc  9
#define PADc 4
#define Bb   4
#define Ss   1024
#define MRr  (Bb * Ss)          // 4096

typedef __attribute__((ext_vector_type(8))) __bf16 bf16x8;
typedef __attribute__((ext_vector_type(4))) float  f32x4;

// split 8 consecutive f32 into hi/lo bf16 fragments
__device__ __forceinline__ void split8(const float* p, bf16x8& hi, bf16x8& lo) {
    float4 x0 = *(const float4*)p;
    float4 x1 = *(const float4*)(p + 4);
    float xs[8] = {x0.x, x0.y, x0.z, x0.w, x1.x, x1.y, x1.z, x1.w};
#pragma unroll
    for (int e = 0; e < 8; ++e) {
        __bf16 hv = (__bf16)xs[e];
        hi[e] = hv;
        lo[e] = (__bf16)(xs[e] - (float)hv);
    }
}

__device__ __forceinline__ void split8r(const float* xs, bf16x8& hi, bf16x8& lo) {
#pragma unroll
    for (int e = 0; e < 8; ++e) {
        __bf16 hv = (__bf16)xs[e];
        hi[e] = hv;
        lo[e] = (__bf16)(xs[e] - (float)hv);
    }
}

// convert 8 consecutive f32 to bf16 (hi only)
__device__ __forceinline__ bf16x8 cvt8(const float* p) {
    float4 x0 = *(const float4*)p;
    float4 x1 = *(const float4*)(p + 4);
    float xs[8] = {x0.x, x0.y, x0.z, x0.w, x1.x, x1.y, x1.z, x1.w};
    bf16x8 h;
#pragma unroll
    for (int e = 0; e < 8; ++e) h[e] = (__bf16)xs[e];
    return h;
}

// ---------------- depthwise conv over sequence (float4 over channels) ----------------
__global__ void k_depthwise(const float* __restrict__ Kin, const float* __restrict__ dww,
                            float* __restrict__ dwseq) {
    int idx = blockIdx.x * 256 + threadIdx.x;      // over B*S*HID/4
    if (idx >= Bb * Ss * HIDC / 4) return;
    int c4 = idx % (HIDC / 4);
    int s  = (idx / (HIDC / 4)) % Ss;
    int b  = idx / ((HIDC / 4) * Ss);
    int c  = c4 * 4;
    float wv[4][KSc];
#pragma unroll
    for (int j = 0; j < 4; ++j)
#pragma unroll
        for (int k = 0; k < KSc; ++k) wv[j][k] = dww[(c + j) * KSc + k];
    float4 acc = {0.f, 0.f, 0.f, 0.f};
#pragma unroll
    for (int k = 0; k < KSc; ++k) {
        int sp = s + k - PADc;
        if (sp >= 0 && sp < Ss) {
            float4 v = *(const float4*)&Kin[(size_t)(b * Ss + sp) * HIDC + c];
            acc.x += v.x * wv[0][k]; acc.y += v.y * wv[1][k];
            acc.z += v.z * wv[2][k]; acc.w += v.w * wv[3][k];
        }
    }
    *(float4*)&dwseq[(size_t)idx * 4] = acc;
}

// ---------------- transposed weight split (z=0..3): LDS-tiled ----------------
__global__ __launch_bounds__(256) void k_wsplit_t(const float* __restrict__ Wq, const float* __restrict__ Wk,
                                                  const float* __restrict__ Wv, const float* __restrict__ coW,
                                                  __bf16* __restrict__ Whi, __bf16* __restrict__ Wlo) {
    int z = blockIdx.z;
    const float* src = (z == 0) ? Wq : (z == 1) ? Wk : (z == 2) ? Wv : coW;
    int n0 = blockIdx.x * 64, k0 = blockIdx.y * 64;
    int tid = threadIdx.x;
    int r = tid >> 2, cq = tid & 3;
    __shared__ float tile[64][65];      // tile[k_local][n_local]
#pragma unroll
    for (int e = 0; e < 4; ++e) {
        float4 v = *(const float4*)&src[(size_t)(k0 + r) * AHc + n0 + cq * 16 + e * 4];
        tile[r][cq * 16 + e * 4 + 0] = v.x;
        tile[r][cq * 16 + e * 4 + 1] = v.y;
        tile[r][cq * 16 + e * 4 + 2] = v.z;
        tile[r][cq * 16 + e * 4 + 3] = v.w;
    }
    __syncthreads();
    float x[16];
#pragma unroll
    for (int e = 0; e < 16; ++e) x[e] = tile[cq * 16 + e][r];
    bf16x8 h0, l0, h1, l1;
    split8r(x, h0, l0);
    split8r(x + 8, h1, l1);
    size_t dst = ((size_t)(z * AHc + n0 + r)) * HIDC + k0 + cq * 16;
    *(bf16x8*)(Whi + dst)     = h0;
    *(bf16x8*)(Whi + dst + 8) = h1;
    *(bf16x8*)(Wlo + dst)     = l0;
    *(bf16x8*)(Wlo + dst + 8) = l1;
}

// ---------------- pw_w split (z=4, already [n][k]) ----------------
__global__ void k_wsplit_c(const float* __restrict__ pww,
                           __bf16* __restrict__ Whi, __bf16* __restrict__ Wlo) {
    int idx = blockIdx.x * 256 + threadIdx.x;      // over AHc*HIDC/8
    if (idx >= AHc * HIDC / 8) return;
    bf16x8 hi, lo;
    split8(pww + (size_t)idx * 8, hi, lo);
    size_t dst = (size_t)4 * AHc * HIDC + (size_t)idx * 8;
    *(bf16x8*)(Whi + dst) = hi;
    *(bf16x8*)(Wlo + dst) = lo;
}

// ---------------- Q/K split for k_attn: qh (hi only), kh+kl ----------------
__global__ void k_qksplit(const float* __restrict__ mq, const float* __restrict__ mk,
                          __bf16* __restrict__ qh, __bf16* __restrict__ kh,
                          __bf16* __restrict__ kl) {
    const int n8 = MRr * AHc / 8;
    int idx = blockIdx.x * 256 + threadIdx.x;
    if (idx >= 2 * n8) return;
    int which = idx / n8, i8 = idx % n8;
    if (which == 0) {
        *(bf16x8*)(qh + (size_t)i8 * 8) = cvt8(mq + (size_t)i8 * 8);
    } else {
        bf16x8 hi, lo;
        split8(mk + (size_t)i8 * 8, hi, lo);
        *(bf16x8*)(kh + (size_t)i8 * 8) = hi;
        *(bf16x8*)(kl + (size_t)i8 * 8) = lo;
    }
}

// ---------------- V transpose (hi bf16 only), LDS-tiled for coalescing ----------------
// vt[(b*H+h)*D + d][s] = (bf16) mv[b*S+s][h*D+d]  — same formula as the round-10
// verified kernel; only the access pattern changed (coalesced reads AND writes).
__global__ __launch_bounds__(256) void k_vtr(const float* __restrict__ mv, __bf16* __restrict__ vt) {
    int bh = blockIdx.y;                 // b*Hh + h
    int s0 = blockIdx.x * 64;
    int b = bh / Hh, h = bh % Hh;
    int tid = threadIdx.x;
    int r = tid >> 2, cq = tid & 3;
    __shared__ float tile[64][65];       // tile[s_local][d_local]
#pragma unroll
    for (int e = 0; e < 4; ++e) {
        float4 v = *(const float4*)&mv[(size_t)(b * Ss + s0 + r) * AHc + h * Dd + cq * 16 + e * 4];
        tile[r][cq * 16 + e * 4 + 0] = v.x;
        tile[r][cq * 16 + e * 4 + 1] = v.y;
        tile[r][cq * 16 + e * 4 + 2] = v.z;
        tile[r][cq * 16 + e * 4 + 3] = v.w;
    }
    __syncthreads();
    // write phase: this thread owns d_local = r, s chunk = cq*16 .. +15
    bf16x8 o0, o1;
#pragma unroll
    for (int e = 0; e < 8; ++e) o0[e] = (__bf16)tile[cq * 16 + e][r];
#pragma unroll
    for (int e = 0; e < 8; ++e) o1[e] = (__bf16)tile[cq * 16 + 8 + e][r];
    size_t dst = ((size_t)bh * Dd + r) * Ss + s0 + cq * 16;
    *(bf16x8*)(vt + dst)     = o0;
    *(bf16x8*)(vt + dst + 8) = o1;
}

// ---------------- bias buffer: [5][384] ----------------
__global__ void k_bias(const float* __restrict__ cob, const float* __restrict__ sepb,
                       float* __restrict__ biasb) {
    int idx = blockIdx.x * 256 + threadIdx.x;
    if (idx >= 5 * AHc) return;
    int z = idx / AHc, n = idx % AHc;
    biasb[idx] = (z == 3) ? cob[n] : (z == 4) ? sepb[n] : 0.f;
}

// ---------------- batched MFMA GEMM (2-term: ah*bh + ah*bl) ----------------
__global__ __launch_bounds__(256) void k_gemm5(
        const float* __restrict__ Q, const float* __restrict__ Kin,
        const float* __restrict__ V, const float* __restrict__ dwseq,
        const __bf16* __restrict__ Whi, const __bf16* __restrict__ Wlo,
        const float* __restrict__ biasb, float* __restrict__ Call) {
    __shared__ __attribute__((aligned(16))) __bf16 As_hi[128 * 40];
    __shared__ __attribute__((aligned(16))) __bf16 Bs_hi[128 * 40];
    __shared__ __attribute__((aligned(16))) __bf16 Bs_lo[128 * 40];

    int z = blockIdx.z;
    const float* Asrc = (z == 0) ? Q : (z == 1) ? Kin : (z <= 3) ? V : dwseq;
    int m0 = blockIdx.y * 128, n0 = blockIdx.x * 128;
    int tid = threadIdx.x;
    int wave = tid >> 6, lane = tid & 63, quad = lane >> 4, l15 = lane & 15;

    int sr = tid >> 1;
    int sk = (tid & 1) * 16;
    const float* Arow = Asrc + (size_t)(m0 + sr) * HIDC + sk;
    const __bf16* BhiRow = Whi + ((size_t)(z * AHc + n0 + sr)) * HIDC + sk;
    const __bf16* BloRow = Wlo + ((size_t)(z * AHc + n0 + sr)) * HIDC + sk;

    f32x4 acc[4][4] = {};

    for (int k0 = 0; k0 < HIDC; k0 += 32) {
        const float* ap = Arow + k0;
        *(bf16x8*)&As_hi[sr * 40 + sk]     = cvt8(ap);
        *(bf16x8*)&As_hi[sr * 40 + sk + 8] = cvt8(ap + 8);
        {
            const __bf16* bh = BhiRow + k0;
            const __bf16* bl = BloRow + k0;
            *(bf16x8*)&Bs_hi[sr * 40 + sk]     = *(const bf16x8*)bh;
            *(bf16x8*)&Bs_hi[sr * 40 + sk + 8] = *(const bf16x8*)(bh + 8);
            *(bf16x8*)&Bs_lo[sr * 40 + sk]     = *(const bf16x8*)bl;
            *(bf16x8*)&Bs_lo[sr * 40 + sk + 8] = *(const bf16x8*)(bl + 8);
        }
        __syncthreads();

        int mrow = (wave >> 1) * 64 + l15;
        int nrow = (wave & 1) * 64 + l15;
        bf16x8 ah[4], bh[4], bl[4];
#pragma unroll
        for (int mt = 0; mt < 4; ++mt)
            ah[mt] = *(bf16x8*)&As_hi[(mrow + mt * 16) * 40 + quad * 8];
#pragma unroll
        for (int nt = 0; nt < 4; ++nt) {
            bh[nt] = *(bf16x8*)&Bs_hi[(nrow + nt * 16) * 40 + quad * 8];
            bl[nt] = *(bf16x8*)&Bs_lo[(nrow + nt * 16) * 40 + quad * 8];
        }
#pragma unroll
        for (int mt = 0; mt < 4; ++mt)
#pragma unroll
            for (int nt = 0; nt < 4; ++nt) {
                acc[mt][nt] = __builtin_amdgcn_mfma_f32_16x16x32_bf16(ah[mt], bh[nt], acc[mt][nt], 0, 0, 0);
                acc[mt][nt] = __builtin_amdgcn_mfma_f32_16x16x32_bf16(ah[mt], bl[nt], acc[mt][nt], 0, 0, 0);
            }
        __syncthreads();
    }

    float* Cz = Call + (size_t)z * MRr * AHc;
    const float* bz = biasb + z * AHc;
#pragma unroll
    for (int nt = 0; nt < 4; ++nt) {
        int n = n0 + (wave & 1) * 64 + nt * 16 + l15;
        float bias = bz[n];
#pragma unroll
        for (int mt = 0; mt < 4; ++mt) {
#pragma unroll
            for (int r = 0; r < 4; ++r) {
                int m = m0 + (wave >> 1) * 64 + mt * 16 + quad * 4 + r;
                Cz[(size_t)m * AHc + n] = acc[mt][nt][r] + bias;
            }
        }
    }
}

// ---------------- conv_attn -> ck linear -> per-head softmax over KS ----------------
__global__ __launch_bounds__(64) void k_ck(const float* __restrict__ mkc, const float* __restrict__ mq,
                                           const float* __restrict__ ckW, const float* __restrict__ ckb,
                                           float* __restrict__ ck_sm) {
    int row = blockIdx.x;            // b*S + s
    int tid = threadIdx.x;
    __shared__ float ca[AHc];
    __shared__ float ckv[Hh * KSc];
    for (int o = tid; o < AHc; o += 64)
        ca[o] = mkc[row * AHc + o] * mq[row * AHc + o];
    __syncthreads();
    if (tid < Hh * KSc) {
        float acc = ckb[tid];
        for (int o = 0; o < AHc; ++o)
            acc += ca[o] * ckW[o * (Hh * KSc) + tid];
        ckv[tid] = acc;
    }
    __syncthreads();
    if (tid < Hh) {
        float m = -3e38f;
#pragma unroll
        for (int k = 0; k < KSc; ++k) m = fmaxf(m, ckv[tid * KSc + k]);
        float e[KSc];
        float s = 0.f;
#pragma unroll
        for (int k = 0; k < KSc; ++k) { e[k] = expf(ckv[tid * KSc + k] - m); s += e[k]; }
        float inv = 1.f / s;
#pragma unroll
        for (int k = 0; k < KSc; ++k) ck_sm[(row * Hh + tid) * KSc + k] = e[k] * inv;
    }
}

// ---------------- dynamic conv output (float4) -> out[.., AH + h*D + d] ----------------
__global__ void k_convout(const float* __restrict__ co, const float* __restrict__ ck_sm,
                          float* __restrict__ out) {
    int idx = blockIdx.x * 256 + threadIdx.x;       // over B*S*AH/4
    if (idx >= Bb * Ss * AHc / 4) return;
    int d4 = idx & 15;
    int h  = (idx >> 4) % Hh;
    int s  = (idx / (AHc / 4)) % Ss;
    int b  = idx / ((AHc / 4) * Ss);
    int row = b * Ss + s;
    const float* ck = ck_sm + (size_t)(row * Hh + h) * KSc;
    float4 acc = {0.f, 0.f, 0.f, 0.f};
#pragma unroll
    for (int k = 0; k < KSc; ++k) {
        int sp = s + k - PADc;
        if (sp >= 0 && sp < Ss) {
            float4 v = *(const float4*)&co[(size_t)(b * Ss + sp) * AHc + h * Dd + d4 * 4];
            float wv = ck[k];
            acc.x += wv * v.x; acc.y += wv * v.y; acc.z += wv * v.z; acc.w += wv * v.w;
        }
    }
    *(float4*)&out[(size_t)row * (2 * AHc) + AHc + h * Dd + d4 * 4] = acc;
}

// ---------------- per-batch td softmax row ----------------
__global__ __launch_bounds__(256) void k_td(const float* __restrict__ td, const int* __restrict__ mask,
                                            float* __restrict__ td_sm) {
    int b = blockIdx.x;
    int tid = threadIdx.x;
    __shared__ float red[256];
    __shared__ float tv[Ss];
    float ls = 0.f;
    for (int j = tid; j < Ss; j += 256) {
        float v = td[b * Ss + j];
        tv[j] = v;
        ls += v * v;
    }
    red[tid] = ls; __syncthreads();
    for (int s = 128; s > 0; s >>= 1) { if (tid < s) red[tid] += red[tid + s]; __syncthreads(); }
    float norm = fmaxf(sqrtf(red[0]), 1e-12f);
    __syncthreads();
    float lm = -3e38f;
    for (int j = tid; j < Ss; j += 256) {
        float v = mask[b * Ss + j] ? tv[j] / norm : -1e4f;
        tv[j] = v;
        lm = fmaxf(lm, v);
    }
    red[tid] = lm; __syncthreads();
    for (int s = 128; s > 0; s >>= 1) { if (tid < s) red[tid] = fmaxf(red[tid], red[tid + s]); __syncthreads(); }
    float m = red[0]; __syncthreads();
    float lsum = 0.f;
    for (int j = tid; j < Ss; j += 256) {
        float e = expf(tv[j] - m);
        tv[j] = e;
        lsum += e;
    }
    red[tid] = lsum; __syncthreads();
    for (int s = 128; s > 0; s >>= 1) { if (tid < s) red[tid] += red[tid + s]; __syncthreads(); }
    float inv = 1.f / red[0];
    __syncthreads();
    for (int j = tid; j < Ss; j += 256)
        td_sm[b * Ss + j] = tv[j] * inv;
}

// ---------------- attention: 2-term MFMA QK^T + wave softmax + 2-term MFMA PV (vT) ------
__device__ __forceinline__ int sidx(int m, int j) {
    return m * 1024 + (j & ~15) + ((j ^ (j >> 6) ^ m) & 15);
}

__global__ __launch_bounds__(256) void k_attn(const __bf16* __restrict__ qh,
                                              const __bf16* __restrict__ kh, const __bf16* __restrict__ kl,
                                              const __bf16* __restrict__ vt,
                                              const int* __restrict__ mask,
                                              const float* __restrict__ td_sm, const float* __restrict__ gammas,
                                              float* __restrict__ out) {
    __shared__ float sc[16 * 1024];      // 64 KB exactly
    int i0 = blockIdx.x * 16;
    int h = blockIdx.y % Hh, b = blockIdx.y / Hh;
    int tid = threadIdx.x;
    int w = tid >> 6, lane = tid & 63, quad = lane >> 4, l15 = lane & 15;
    int jw = w * 256;                     // this wave's j-range [jw, jw+256)

    // ---- phase 1: QK^T via MFMA: q_hi*(k_hi + k_lo) ----
    bf16x8 a_hi[2];
    {
        size_t qoff = (size_t)(b * Ss + i0 + l15) * AHc + h * Dd + quad * 8;
        a_hi[0] = *(const bf16x8*)(qh + qoff);
        a_hi[1] = *(const bf16x8*)(qh + qoff + 32);
    }
#pragma unroll 2
    for (int t = 0; t < 16; ++t) {
        int jt = jw + t * 16;
        size_t koff = (size_t)(b * Ss + jt + l15) * AHc + h * Dd + quad * 8;
        f32x4 acc = {0.f, 0.f, 0.f, 0.f};
#pragma unroll
        for (int kc = 0; kc < 2; ++kc) {
            bf16x8 khv = *(const bf16x8*)(kh + koff + kc * 32);
            bf16x8 klv = *(const bf16x8*)(kl + koff + kc * 32);
            acc = __builtin_amdgcn_mfma_f32_16x16x32_bf16(a_hi[kc], khv, acc, 0, 0, 0);
            acc = __builtin_amdgcn_mfma_f32_16x16x32_bf16(a_hi[kc], klv, acc, 0, 0, 0);
        }
#pragma unroll
        for (int r = 0; r < 4; ++r)
            sc[sidx(quad * 4 + r, jt + l15)] = acc[r] * 0.125f;   // C: col=l15, row=quad*4+r
    }
    __syncthreads();

    // ---- phase 2: softmax -> cumsum -> decay -> softmax2, wave owns rows w*4..w*4+3 ----
    const int* mrow = mask + b * Ss;
    const float* tdrow = td_sm + b * Ss;
    float gamma = -log1pf(expf(gammas[h]));   // -softplus
    int jb = lane << 4;
    int marr[16];
    {
        const int4* mp = (const int4*)(mrow + jb);
#pragma unroll
        for (int k = 0; k < 4; ++k) ((int4*)marr)[k] = mp[k];
    }
    float tdv[16];
    {
        const float4* tp = (const float4*)(tdrow + jb);
#pragma unroll
        for (int k = 0; k < 4; ++k) ((float4*)tdv)[k] = tp[k];
    }

#pragma unroll
    for (int r4 = 0; r4 < 4; ++r4) {
        int m = w * 4 + r4;
        int i = i0 + m;
        float s[16], p[16];
#pragma unroll
        for (int jj = 0; jj < 16; ++jj) s[jj] = sc[sidx(m, jb + jj)];
        float mx = -1e30f;
#pragma unroll
        for (int jj = 0; jj < 16; ++jj) mx = fmaxf(mx, marr[jj] ? s[jj] : -1e30f);
        mx = fmaxf(mx, __shfl_xor(mx, 1));  mx = fmaxf(mx, __shfl_xor(mx, 2));
        mx = fmaxf(mx, __shfl_xor(mx, 4));  mx = fmaxf(mx, __shfl_xor(mx, 8));
        mx = fmaxf(mx, __shfl_xor(mx, 16)); mx = fmaxf(mx, __shfl_xor(mx, 32));
#pragma unroll
        for (int jj = 0; jj < 16; ++jj) p[jj] = marr[jj] ? __expf(s[jj] - mx) : 0.f;
#pragma unroll
        for (int jj = 1; jj < 16; ++jj) p[jj] += p[jj - 1];
        float t = p[15];
        float incl = t;
#pragma unroll
        for (int dlt = 1; dlt < 64; dlt <<= 1) {
            float v = __shfl_up(incl, dlt);
            if (lane >= dlt) incl += v;
        }
        float off = incl - t;
        float tot = __shfl(incl, 63);
        float inv = 1.f / fmaxf(tot, 1e-30f);
        float mx2 = -1e30f;
#pragma unroll
        for (int jj = 0; jj < 16; ++jj) {
            int j = jb + jj;
            float cum = p[jj] + off;
            float pos = fabsf((float)(j - i));
            float ds = sqrtf(fmaxf((tot - cum) * inv * pos, 0.f));
            float te = fminf(fmaxf(__expf(ds * gamma), 1e-5f), 1e5f);
            float mult = te - ((j < i) ? tdv[jj] : 0.f);
            float s2 = marr[jj] ? s[jj] * mult : -1e8f;
            s[jj] = s2;
            mx2 = fmaxf(mx2, s2);
        }
        mx2 = fmaxf(mx2, __shfl_xor(mx2, 1));  mx2 = fmaxf(mx2, __shfl_xor(mx2, 2));
        mx2 = fmaxf(mx2, __shfl_xor(mx2, 4));  mx2 = fmaxf(mx2, __shfl_xor(mx2, 8));
        mx2 = fmaxf(mx2, __shfl_xor(mx2, 16)); mx2 = fmaxf(mx2, __shfl_xor(mx2, 32));
        float sm = 0.f;
#pragma unroll
        for (int jj = 0; jj < 16; ++jj) { s[jj] = __expf(s[jj] - mx2); sm += s[jj]; }
        sm += __shfl_xor(sm, 1);  sm += __shfl_xor(sm, 2);
        sm += __shfl_xor(sm, 4);  sm += __shfl_xor(sm, 8);
        sm += __shfl_xor(sm, 16); sm += __shfl_xor(sm, 32);
        float inv2 = 1.f / sm;
#pragma unroll
        for (int jj = 0; jj < 16; ++jj) sc[sidx(m, jb + jj)] = s[jj] * inv2;
    }
    __syncthreads();

    // ---- phase 3: PV via MFMA: (p_hi + p_lo) * v_hi; V^T bf16 [d][s] vector loads ----
    f32x4 oacc[4] = {};
    const __bf16* vtb = vt + (size_t)(b * Hh + h) * Dd * Ss;
#pragma unroll 2
    for (int kc = 0; kc < 8; ++kc) {
        int j0 = jw + kc * 32 + quad * 8;        // this lane's 8 j indices (k = quad*8+e)
        float x[8];
#pragma unroll
        for (int jj = 0; jj < 8; ++jj) x[jj] = sc[sidx(l15, j0 + jj)];
        bf16x8 p_hi, p_lo;
        split8r(x, p_hi, p_lo);
#pragma unroll
        for (int nt = 0; nt < 4; ++nt) {
            int d = nt * 16 + l15;
            bf16x8 vv = *(const bf16x8*)(vtb + (size_t)d * Ss + j0);
            oacc[nt] = __builtin_amdgcn_mfma_f32_16x16x32_bf16(p_hi, vv, oacc[nt], 0, 0, 0);
            oacc[nt] = __builtin_amdgcn_mfma_f32_16x16x32_bf16(p_lo, vv, oacc[nt], 0, 0, 0);
        }
    }
    __syncthreads();                      // all waves done reading sc before reuse
#pragma unroll
    for (int nt = 0; nt < 4; ++nt)
#pragma unroll
        for (int r = 0; r < 4; ++r)
            sc[w * 1024 + (quad * 4 + r) * 64 + nt * 16 + l15] = oacc[nt][r];
    __syncthreads();
#pragma unroll
    for (int e = 0; e < 4; ++e) {
        int idx = e * 256 + tid;
        int m = idx >> 6, dd = idx & 63;
        float v = sc[idx] + sc[1024 + idx] + sc[2048 + idx] + sc[3072 + idx];
        out[(size_t)(b * Ss + i0 + m) * (2 * AHc) + h * Dd + dd] = v;
    }
}

extern "C" void kernel_launch(void* const* d_in, const int* in_sizes, int n_in,
                              void* d_out, int out_size, void* d_ws, size_t ws_size,
                              hipStream_t stream) {
    const float* Q    = (const float*)d_in[0];
    const float* Kin  = (const float*)d_in[1];
    const float* V    = (const float*)d_in[2];
    const float* td   = (const float*)d_in[3];
    const int*   mask = (const int*)d_in[4];
    const float* Wq   = (const float*)d_in[5];
    const float* Wk   = (const float*)d_in[6];
    const float* Wv   = (const float*)d_in[7];
    const float* dww  = (const float*)d_in[8];
    const float* pww  = (const float*)d_in[9];
    const float* sepb = (const float*)d_in[10];
    const float* ckW  = (const float*)d_in[11];
    const float* ckb  = (const float*)d_in[12];
    const float* coW  = (const float*)d_in[13];
    const float* cob  = (const float*)d_in[14];
    const float* gam  = (const float*)d_in[15];
    float* out = (float*)d_out;
    float* ws = (float*)d_ws;

    float* mq    = ws;                              // z=0 C
    float* mk    = mq    + (size_t)MRr * AHc;       // z=1
    float* mv    = mk    + (size_t)MRr * AHc;       // z=2
    float* co    = mv    + (size_t)MRr * AHc;       // z=3
    float* mkc   = co    + (size_t)MRr * AHc;       // z=4
    float* dwseq = mkc   + (size_t)MRr * AHc;       // MR*HID f32 (dead after k_gemm5)
    float* cksm  = dwseq + (size_t)MRr * HIDC;      // MR*H*KS
    float* tdsm  = cksm  + (size_t)MRr * Hh * KSc;  // B*S
    float* biasb = tdsm  + (size_t)Bb * Ss;         // 5*384

    // d_out doubles as scratch for split weights (consumed by k_gemm5, then overwritten)
    __bf16* Whi = (__bf16*)d_out;
    __bf16* Wlo = Whi + (size_t)5 * AHc * HIDC;
    // qh/kh/kl/vt overlay the dead dwseq region: 4 * MR*AH bf16 == MR*HID f32 exactly
    __bf16* qh = (__bf16*)dwseq;
    __bf16* kh = qh + (size_t)MRr * AHc;
    __bf16* kl = kh + (size_t)MRr * AHc;
    __bf16* vt = kl + (size_t)MRr * AHc;

    dim3 gt(AHc / 64, HIDC / 64, 4);    // 6 x 12 x 4
    k_wsplit_t<<<gt, 256, 0, stream>>>(Wq, Wk, Wv, coW, Whi, Wlo);
    k_wsplit_c<<<(AHc * HIDC / 8 + 255) / 256, 256, 0, stream>>>(pww, Whi, Wlo);
    k_depthwise<<<(MRr * HIDC / 4 + 255) / 256, 256, 0, stream>>>(Kin, dww, dwseq);
    k_bias<<<(5 * AHc + 255) / 256, 256, 0, stream>>>(cob, sepb, biasb);

    dim3 gg(AHc / 128, MRr / 128, 5);   // 3 x 32 x 5
    k_gemm5<<<gg, 256, 0, stream>>>(Q, Kin, V, dwseq, Whi, Wlo, biasb, mq);

    k_qksplit<<<(2 * MRr * AHc / 8 + 255) / 256, 256, 0, stream>>>(mq, mk, qh, kh, kl);
    dim3 gv(Ss / 64, Bb * Hh);          // 16 x 24
    k_vtr<<<gv, 256, 0, stream>>>(mv, vt);
    k_ck<<<MRr, 64, 0, stream>>>(mkc, mq, ckW, ckb, cksm);
    k_convout<<<(MRr * AHc / 4 + 255) / 256, 256, 0, stream>>>(co, cksm, out);
    k_td<<<Bb, 256, 0, stream>>>(td, mask, tdsm);

    dim3 ga(Ss / 16, Bb * Hh);          // 64 x 24
    k_attn<<<ga, 256, 0, stream>>>(qh, kh, kl, vt, mask, tdsm, gam, out);
}